// Round 9
// baseline (168.920 us; speedup 1.0000x reference)
//
#include <hip/hip_runtime.h>
#include <math.h>

#define Bb 4
#define Tt 1024
#define Cc 512
#define Hh 4
#define Dd 128
#define Mrows (Bb*Tt)   // 4096
#define NC 32           // chunks
#define CL 32           // chunk length
#define AUGB_CB 18432   // u16 per (c,bh): 16 ig * 144 j * 8

typedef unsigned short u16;
typedef __attribute__((ext_vector_type(8))) short bf16x8;
typedef __attribute__((ext_vector_type(4))) float f32x4;

__device__ __forceinline__ u16 f2bf(float f) {
  unsigned u = __float_as_uint(f);
  unsigned r = (u + 0x7fffu + ((u >> 16) & 1u)) >> 16;
  return (u16)r;
}
__device__ __forceinline__ float bf2f(u16 v) {
  return __uint_as_float((unsigned)v << 16);
}
__device__ __forceinline__ unsigned pack2(float a, float b) {
  return (unsigned)f2bf(a) | ((unsigned)f2bf(b) << 16);
}
// rms reciprocal from 4 ssq partials for a row
__device__ __forceinline__ float rms_r(const float* __restrict__ ssqp, int zsel, int row) {
  const float* p = ssqp + (size_t)zsel*4*Mrows + row;
  float s2 = p[0] + p[Mrows] + p[2*Mrows] + p[3*Mrows];
  float norm = sqrtf(s2) * 0.044194173824159216f;  // /sqrt(512)
  return 1.f / (norm + 1e-8f);
}

// -------- fused LN1 + time-shift mix -> 4x blocked bf16 [C/8][M][8] --------
__global__ __launch_bounds__(256) void ln1mix_kernel(const float* __restrict__ x,
    const float* __restrict__ g, const float* __restrict__ bta,
    const float* __restrict__ tmq, const float* __restrict__ tmk,
    const float* __restrict__ tmv, const float* __restrict__ tmg,
    u16* __restrict__ xqb, u16* __restrict__ xkb,
    u16* __restrict__ xvb, u16* __restrict__ xgb)
{
  int m = blockIdx.x, tid = threadIdx.x;
  const float* xr = x + (size_t)m * Cc;
  float v0 = xr[tid], v1 = xr[tid + 256];
  bool has = (m & (Tt-1)) != 0;
  float u0 = 0.f, u1 = 0.f;
  if (has) { u0 = xr[tid - Cc]; u1 = xr[(int)tid + 256 - Cc]; }
  float sa = v0 + v1, qa = v0*v0 + v1*v1;
  float sb = u0 + u1, qb = u0*u0 + u1*u1;
  #pragma unroll
  for (int off = 32; off > 0; off >>= 1) {
    sa += __shfl_down(sa, off, 64); qa += __shfl_down(qa, off, 64);
    sb += __shfl_down(sb, off, 64); qb += __shfl_down(qb, off, 64);
  }
  __shared__ float r4[4][4];
  int w = tid >> 6;
  if ((tid & 63) == 0) { r4[w][0]=sa; r4[w][1]=qa; r4[w][2]=sb; r4[w][3]=qb; }
  __syncthreads();
  float Sa = r4[0][0]+r4[1][0]+r4[2][0]+r4[3][0];
  float Qa = r4[0][1]+r4[1][1]+r4[2][1]+r4[3][1];
  float Sb = r4[0][2]+r4[1][2]+r4[2][2]+r4[3][2];
  float Qb = r4[0][3]+r4[1][3]+r4[2][3]+r4[3][3];
  float ma = Sa*(1.f/Cc), va = Qa*(1.f/Cc) - ma*ma, ia = rsqrtf(va + 1e-5f);
  float mb = Sb*(1.f/Cc), vb = Qb*(1.f/Cc) - mb*mb, ib = rsqrtf(vb + 1e-5f);
  #pragma unroll
  for (int half = 0; half < 2; ++half) {
    int c = tid + half*256;
    float v = half ? v1 : v0, u = half ? u1 : u0;
    float hv = g[c]*(v - ma)*ia + bta[c];
    float pv = has ? (g[c]*(u - mb)*ib + bta[c]) : 0.f;
    size_t off = ((size_t)(c >> 3) * Mrows + m) * 8 + (c & 7);
    float tq = tmq[c], tk = tmk[c], tv = tmv[c], tg = tmg[c];
    xqb[off] = f2bf(hv*tq + pv*(1.f-tq));
    xkb[off] = f2bf(hv*tk + pv*(1.f-tk));
    xvb[off] = f2bf(hv*tv + pv*(1.f-tv));
    xgb[off] = f2bf(hv*tg + pv*(1.f-tg));
  }
}

// --------- fused: x1 = x + p0 + p1; h2b = LN(x1) blocked bf16 ---------
__global__ __launch_bounds__(256) void ln2b_kernel(const float* __restrict__ x,
    const float* __restrict__ p0, const float* __restrict__ p1,
    const float* __restrict__ g, const float* __restrict__ bta,
    float* __restrict__ x1, u16* __restrict__ out)
{
  int row = blockIdx.x, tid = threadIdx.x;
  size_t r0 = (size_t)row * Cc + tid, r1 = r0 + 256;
  float v0 = x[r0] + p0[r0] + p1[r0];
  float v1 = x[r1] + p0[r1] + p1[r1];
  x1[r0] = v0; x1[r1] = v1;
  float s = v0 + v1, s2 = v0*v0 + v1*v1;
  #pragma unroll
  for (int off = 32; off > 0; off >>= 1) {
    s  += __shfl_down(s,  off, 64);
    s2 += __shfl_down(s2, off, 64);
  }
  __shared__ float rs[4], rq[4];
  int w = tid >> 6;
  if ((tid & 63) == 0) { rs[w] = s; rq[w] = s2; }
  __syncthreads();
  float S  = rs[0]+rs[1]+rs[2]+rs[3];
  float S2 = rq[0]+rq[1]+rq[2]+rq[3];
  float mean = S * (1.0f/Cc);
  float var  = S2 * (1.0f/Cc) - mean*mean;
  float inv = rsqrtf(var + 1e-5f);
  int c0 = tid, c1 = tid + 256;
  float o0 = g[c0] * (v0-mean)*inv + bta[c0];
  float o1 = g[c1] * (v1-mean)*inv + bta[c1];
  out[((size_t)(c0 >> 3) * Mrows + row) * 8 + (c0 & 7)] = f2bf(o0);
  out[((size_t)(c1 >> 3) * Mrows + row) * 8 + (c1 & 7)] = f2bf(o1);
}

// ---------------- ALL weights fp32 -> blocked bf16, one dispatch ----------------
__global__ __launch_bounds__(256) void wconv_all_kernel(
    const float* __restrict__ Wq, const float* __restrict__ Wk,
    const float* __restrict__ Wv, const float* __restrict__ Wg,
    const float* __restrict__ Wo, const float* __restrict__ W1,
    const float* __restrict__ W2, u16* __restrict__ out)
{
  int blk = blockIdx.x;
  const float* src; u16* dst; int K, nshift;
  if (blk < 640) {
    int wsel = blk >> 7;
    src = wsel==0?Wq:wsel==1?Wk:wsel==2?Wv:wsel==3?Wg:Wo;
    dst = out + (size_t)wsel*262144; K = 512; nshift = 9; blk &= 127;
  } else if (blk < 1152) {
    src = W1; dst = out + (size_t)5*262144; K = 512; nshift = 11; blk -= 640;
  } else {
    src = W2; dst = out + (size_t)5*262144 + 1048576; K = 2048; nshift = 9; blk -= 1152;
  }
  int i = blk*256 + threadIdx.x;
  int n = i & ((1 << nshift) - 1), kg = i >> nshift;
  const float* p = src + (size_t)n * K + kg * 8;
  float4 a = *(const float4*)p, b = *(const float4*)(p + 4);
  uint4 o;
  o.x = pack2(a.x, a.y); o.y = pack2(a.z, a.w);
  o.z = pack2(b.x, b.y); o.w = pack2(b.z, b.w);
  *(uint4*)(dst + (size_t)i * 8) = o;
}

// ---------------- bf16 MFMA GEMM core (templated dims) ----------------
// 3-buffer LDS, depth-2 prefetch, counted vmcnt, 1 barrier/K-step.
// Optional ssq: per-block row sum-of-squares partials (deterministic LDS tree).
template<int MR, int NR, int KR>
__device__ __forceinline__ void gemm_core(const u16* __restrict__ A,
    const u16* __restrict__ W, const float* __restrict__ res,
    float* __restrict__ outf, u16* __restrict__ outb, int act,
    int m0, int n0, u16* Asm, u16* Bsm, float* __restrict__ ssq)
{
  const int tid = threadIdx.x, w = tid >> 6, l = tid & 63;
  const int wr = w >> 1, wc = w & 1;
  f32x4 acc[4][4];
  #pragma unroll
  for (int i = 0; i < 4; ++i)
    #pragma unroll
    for (int j = 0; j < 4; ++j) acc[i][j] = (f32x4){0.f,0.f,0.f,0.f};
  const int kgl = l >> 4, rl = l & 15;
  const int q = w * 4;

  #define STAGE(KT, BUF) do {                                               \
    _Pragma("unroll")                                                       \
    for (int ii = 0; ii < 4; ++ii) {                                        \
      int qq = q + ii;                                                      \
      int isB = qq >> 3, idx = qq & 7, kg = idx >> 1, hf = idx & 1;         \
      const u16* src = isB                                                  \
        ? W + ((size_t)((KT)*4 + kg) * NR + n0 + hf*64 + l) * 8             \
        : A + ((size_t)((KT)*4 + kg) * MR + m0 + hf*64 + l) * 8;            \
      u16* dst = (isB ? Bsm : Asm) + (BUF)*4096 + (kg * 128 + hf * 64) * 8; \
      __builtin_amdgcn_global_load_lds(                                     \
          (const __attribute__((address_space(1))) void*)src,               \
          (__attribute__((address_space(3))) void*)dst, 16, 0, 0);          \
    }                                                                       \
  } while (0)

  constexpr int nk = KR >> 5;
  STAGE(0, 0); STAGE(1, 1);
  int cur = 0;
  for (int kt = 0; kt < nk; ++kt) {
    if (kt == nk - 1) asm volatile("s_waitcnt vmcnt(0)" ::: "memory");
    else              asm volatile("s_waitcnt vmcnt(4)" ::: "memory");
    __builtin_amdgcn_s_barrier();
    bf16x8 af[4], bfr[4];
    #pragma unroll
    for (int f = 0; f < 4; ++f)
      af[f] = *(const bf16x8*)&Asm[cur*4096 + (kgl*128 + wr*64 + f*16 + rl) * 8];
    #pragma unroll
    for (int f = 0; f < 4; ++f)
      bfr[f] = *(const bf16x8*)&Bsm[cur*4096 + (kgl*128 + wc*64 + f*16 + rl) * 8];
    if (kt + 2 < nk) {
      int nb = cur + 2; if (nb >= 3) nb -= 3;
      STAGE(kt + 2, nb);
    }
    __builtin_amdgcn_s_setprio(1);
    #pragma unroll
    for (int i = 0; i < 4; ++i)
      #pragma unroll
      for (int j = 0; j < 4; ++j)
        acc[i][j] = __builtin_amdgcn_mfma_f32_16x16x32_bf16(af[i], bfr[j], acc[i][j], 0, 0, 0);
    __builtin_amdgcn_s_setprio(0);
    if (++cur == 3) cur = 0;
  }
  #undef STAGE

  const int rbase = (l >> 4) * 4, cn = l & 15;
  #pragma unroll
  for (int i = 0; i < 4; ++i) {
    #pragma unroll
    for (int j = 0; j < 4; ++j) {
      #pragma unroll
      for (int r = 0; r < 4; ++r) {
        int m = m0 + wr*64 + i*16 + rbase + r;
        int n = n0 + wc*64 + j*16 + cn;
        float vv = acc[i][j][r];
        if (res) vv += res[(size_t)m * NR + n];
        if (act == 1) vv = 0.5f*vv*(1.f + erff(vv * 0.70710678118f));
        else if (act == 2) vv = 1.f/(1.f + expf(-vv));
        if (outb) outb[((size_t)(n >> 3) * MR + m) * 8 + (n & 7)] = f2bf(vv);
        else outf[(size_t)m * NR + n] = vv;
      }
    }
  }

  if (ssq) {   // deterministic per-block row ssq partials into ssq[m0..m0+127]
    __syncthreads();                      // all LDS reads of Asm done
    float* red2 = (float*)Asm;            // [128][32] = 16 KB
    #pragma unroll
    for (int i = 0; i < 4; ++i) {
      #pragma unroll
      for (int r = 0; r < 4; ++r) {
        int row_local = wr*64 + i*16 + rbase + r;
        float sq = 0.f;
        #pragma unroll
        for (int j = 0; j < 4; ++j) { float t = acc[i][j][r]; sq += t*t; }
        red2[row_local*32 + wc*16 + cn] = sq;
      }
    }
    __syncthreads();
    if (tid < 128) {
      float ssum = 0.f;
      #pragma unroll
      for (int u2 = 0; u2 < 32; ++u2) ssum += red2[tid*32 + u2];
      ssq[m0 + tid] = ssum;
    }
  }
}

__global__ __launch_bounds__(256) void gemm_qkvg(const u16* __restrict__ xall,
    const u16* __restrict__ Wall, float* __restrict__ outall, float* __restrict__ ssqp)
{
  __shared__ __align__(16) u16 Asm[3*4096];
  __shared__ __align__(16) u16 Bsm[3*4096];
  int z = blockIdx.z;
  const size_t E = (size_t)Mrows * Cc;
  float* ssq = (z < 2) ? ssqp + ((size_t)z*4 + blockIdx.x)*Mrows : nullptr;
  gemm_core<Mrows,512,512>(xall + z*E, Wall + (size_t)z*262144, nullptr,
            outall + z*E, nullptr, z == 3 ? 2 : 0,
            blockIdx.y * 128, blockIdx.x * 128, Asm, Bsm, ssq);
}

__global__ __launch_bounds__(256) void gemm_wo(const u16* __restrict__ A,
    const u16* __restrict__ W, float* __restrict__ pbuf)
{
  __shared__ __align__(16) u16 Asm[3*4096];
  __shared__ __align__(16) u16 Bsm[3*4096];
  int z = blockIdx.z;
  const size_t E = (size_t)Mrows * Cc;
  gemm_core<Mrows,512,256>(A + (size_t)z*32*Mrows*8, W + (size_t)z*32*512*8, nullptr,
            pbuf + z*E, nullptr, 0, blockIdx.y * 128, blockIdx.x * 128, Asm, Bsm, nullptr);
}

__global__ __launch_bounds__(256) void gemm_w1(const u16* __restrict__ A,
    const u16* __restrict__ W, u16* __restrict__ outb)
{
  __shared__ __align__(16) u16 Asm[3*4096];
  __shared__ __align__(16) u16 Bsm[3*4096];
  gemm_core<Mrows,2048,512>(A, W, nullptr, nullptr, outb, 1,
            blockIdx.y * 128, blockIdx.x * 128, Asm, Bsm, nullptr);
}

__global__ __launch_bounds__(256) void gemm_w2(const u16* __restrict__ A,
    const u16* __restrict__ W, float* __restrict__ pbuf)
{
  __shared__ __align__(16) u16 Asm[3*4096];
  __shared__ __align__(16) u16 Bsm[3*4096];
  int z = blockIdx.z;
  const size_t E = (size_t)Mrows * Cc;
  gemm_core<Mrows,512,512>(A + (size_t)z*64*Mrows*8, W + (size_t)z*64*512*8, nullptr,
            pbuf + z*E, nullptr, 0, blockIdx.y * 128, blockIdx.x * 128, Asm, Bsm, nullptr);
}

// ---------------- out = x1 + p0+p1+p2+p3 ----------------
__global__ __launch_bounds__(256) void reduce4_kernel(const float* __restrict__ x1,
    const float* __restrict__ p, float* __restrict__ out)
{
  const size_t E = (size_t)Mrows * Cc;
  size_t f = ((size_t)blockIdx.x * 256 + threadIdx.x) * 4;
  float4 a = *(const float4*)(x1 + f);
  float4 q0 = *(const float4*)(p + f);
  float4 q1 = *(const float4*)(p + E + f);
  float4 q2 = *(const float4*)(p + 2*E + f);
  float4 q3 = *(const float4*)(p + 3*E + f);
  float4 o;
  o.x = a.x + q0.x + q1.x + q2.x + q3.x;
  o.y = a.y + q0.y + q1.y + q2.y + q3.y;
  o.z = a.z + q0.z + q1.z + q2.z + q3.z;
  o.w = a.w + q0.w + q1.w + q2.w + q3.w;
  *(float4*)(out + f) = o;
}

// ---------------- Phase A: chunk-local end state, exp(rms) fused, bf16 blocked out ----
__global__ __launch_bounds__(256) void chunk_state_kernel(const float* __restrict__ k,
    const float* __restrict__ v, const float* __restrict__ td,
    const float* __restrict__ rsc, const float* __restrict__ ssqp,
    u16* __restrict__ Augl)
{
  __shared__ float k_lds[CL][Dd];
  __shared__ float v_lds[CL][Dd];
  int blk = blockIdx.x; int c = blk & (NC-1); int bh = blk >> 5;
  int b = bh >> 2, h = bh & 3;
  int tid = threadIdx.x;
  size_t base = ((size_t)b*Tt + (size_t)c*CL)*Cc + h*Dd;
  #pragma unroll
  for (int r = 0; r < 4; ++r) {
    int idx4 = r*256 + tid;
    int s = idx4 >> 5; int i4 = (idx4 & 31) << 2;
    float rk = rms_r(ssqp, 1, b*Tt + c*CL + s);
    float4 kr = *(const float4*)&k[base + (size_t)s*Cc + i4];
    k_lds[s][i4+0] = expf(rsc[h*Dd+i4+0] * kr.x * rk);
    k_lds[s][i4+1] = expf(rsc[h*Dd+i4+1] * kr.y * rk);
    k_lds[s][i4+2] = expf(rsc[h*Dd+i4+2] * kr.z * rk);
    k_lds[s][i4+3] = expf(rsc[h*Dd+i4+3] * kr.w * rk);
    *(float4*)&v_lds[s][i4] = *(const float4*)&v[base + (size_t)s*Cc + i4];
  }
  __syncthreads();
  int iq = tid >> 3; int i0 = iq << 2;
  int jg = tid & 7;  int j0 = jg << 4;
  float lam4[4], powv[4], zacc[4];
  #pragma unroll
  for (int ci=0; ci<4; ++ci) {
    lam4[ci] = expf(-expf(td[h*Dd + i0 + ci]));
    powv[ci] = 1.f; zacc[ci] = 0.f;
  }
  float acc[4][16];
  #pragma unroll
  for (int ci=0; ci<4; ++ci)
    #pragma unroll
    for (int jj=0; jj<16; ++jj) acc[ci][jj] = 0.f;

  for (int s = CL-1; s >= 0; --s) {
    float4 k4 = *(const float4*)&k_lds[s][i0];
    float kw0 = powv[0]*k4.x, kw1 = powv[1]*k4.y, kw2 = powv[2]*k4.z, kw3 = powv[3]*k4.w;
    zacc[0]+=kw0; zacc[1]+=kw1; zacc[2]+=kw2; zacc[3]+=kw3;
    #pragma unroll
    for (int q4 = 0; q4 < 4; ++q4) {
      float4 v4 = *(const float4*)&v_lds[s][j0 + q4*4];
      float vv[4] = {v4.x, v4.y, v4.z, v4.w};
      #pragma unroll
      for (int u=0; u<4; ++u) {
        acc[0][q4*4+u] += kw0*vv[u];
        acc[1][q4*4+u] += kw1*vv[u];
        acc[2][q4*4+u] += kw2*vv[u];
        acc[3][q4*4+u] += kw3*vv[u];
      }
    }
    powv[0]*=lam4[0]; powv[1]*=lam4[1]; powv[2]*=lam4[2]; powv[3]*=lam4[3];
  }
  u16* aug = Augl + ((size_t)c*16 + bh)*AUGB_CB;
  const int ig = i0 >> 3, isub = i0 & 7;
  #pragma unroll
  for (int jj=0; jj<16; ++jj) {
    int j = j0 + jj;
    uint2 pk;
    pk.x = pack2(acc[0][jj], acc[1][jj]);
    pk.y = pack2(acc[2][jj], acc[3][jj]);
    *(uint2*)&aug[(size_t)ig*1152 + (size_t)j*8 + isub] = pk;
  }
  if (jg == 0) {
    uint2 pk;
    pk.x = pack2(zacc[0], zacc[1]);
    pk.y = pack2(zacc[2], zacc[3]);
    *(uint2*)&aug[(size_t)ig*1152 + 128*8 + isub] = pk;
  }
}

// ---------------- Phase B: inter-chunk prefix scan (bf16 in/out, fp32 accum) ---------
__global__ __launch_bounds__(256) void combine_kernel(const u16* __restrict__ Augl,
    const float* __restrict__ td, u16* __restrict__ Augb)
{
  int idx = blockIdx.x*256 + threadIdx.x;   // [0, 129*128)
  if (idx >= 129*128) return;
  int bh = blockIdx.y; int h = bh & 3;
  int j = idx >> 7, i = idx & 127;
  size_t aoff = (size_t)(i >> 3) * 1152 + (size_t)j * 8 + (i & 7);
  float lamL = expf(-expf(td[h*Dd + i]) * (float)CL);
  const u16* pl = Augl + (size_t)bh*AUGB_CB + aoff;
  u16* pi = Augb + (size_t)bh*AUGB_CB + aoff;
  float prev = 0.f;
  const size_t cstr = (size_t)16*AUGB_CB;
  for (int c = 0; c < NC; ++c) {
    float val = bf2f(pl[c*cstr]);
    pi[c*cstr] = f2bf(prev);
    prev = lamL*prev + val;
  }
}

// ---------------- Phase C: chunked MFMA scan, exp(rms) fused; gatt -> blocked bf16 ---
__global__ __launch_bounds__(256, 2) void scan_mfma_kernel(
    const float* __restrict__ q, const float* __restrict__ k,
    const float* __restrict__ v, const float* __restrict__ td,
    const float* __restrict__ rsc, const float* __restrict__ ssqp,
    const u16* __restrict__ Augb, const float* __restrict__ gmat,
    u16* __restrict__ out)
{
  __shared__ float k_lds[32*192];
  __shared__ u16  qfrag[32*128];
  __shared__ u16  vfrag[4*1152];
  __shared__ float P32[32*33];
  __shared__ u16  pfrag[32*32];
  __shared__ float lam_lds[128];
  __shared__ float zbuf[32];

  const int tid = threadIdx.x;
  const int blk = blockIdx.x; const int c = blk & 31, bh = blk >> 5;
  const int b = bh >> 2, h = bh & 3;
  const int w = tid >> 6, l = tid & 63;
  const int t = (w << 3) + (l >> 3);
  const int is = l & 7;

  if (tid < 128) lam_lds[tid] = expf(-expf(td[h*Dd + tid]));

  const int grow = b*Tt + c*CL + t;
  const size_t rowbase = ((size_t)grow)*Cc + h*Dd + is*16;
  const float rq = rms_r(ssqp, 0, grow);
  const float rk = rms_r(ssqp, 1, grow);

  float qv[16];
  {
    #pragma unroll
    for (int c4 = 0; c4 < 4; ++c4) {
      float4 q4 = *(const float4*)(q + rowbase + c4*4);
      int e0 = c4*4;
      qv[e0+0] = expf(rsc[h*Dd+is*16+e0+0] * q4.x * rq);
      qv[e0+1] = expf(rsc[h*Dd+is*16+e0+1] * q4.y * rq);
      qv[e0+2] = expf(rsc[h*Dd+is*16+e0+2] * q4.z * rq);
      qv[e0+3] = expf(rsc[h*Dd+is*16+e0+3] * q4.w * rq);
    }
    float lt = (float)(t + 1);
    u16 qt[16];
    #pragma unroll
    for (int e = 0; e < 16; ++e) {
      float el2 = -expf(td[h*Dd + is*16 + e]) * 1.4426950408889634f;
      qt[e] = f2bf(qv[e] * exp2f(el2 * lt));
    }
    #pragma unroll
    for (int hf = 0; hf < 2; ++hf) {
      int k8 = is*2 + hf;
      uint4 pk;
      pk.x = (unsigned)qt[hf*8+0] | ((unsigned)qt[hf*8+1]<<16);
      pk.y = (unsigned)qt[hf*8+2] | ((unsigned)qt[hf*8+3]<<16);
      pk.z = (unsigned)qt[hf*8+4] | ((unsigned)qt[hf*8+5]<<16);
      pk.w = (unsigned)qt[hf*8+6] | ((unsigned)qt[hf*8+7]<<16);
      *(uint4*)&qfrag[t*128 + ((k8 ^ (t&7))<<3)] = pk;
    }
  }
  #pragma unroll
  for (int c4 = 0; c4 < 4; ++c4) {
    float4 k4 = *(const float4*)(k + rowbase + c4*4);
    int e0 = is*16 + c4*4;
    k_lds[t*192 + is*24 + c4*4+0] = expf(rsc[h*Dd+e0+0] * k4.x * rk);
    k_lds[t*192 + is*24 + c4*4+1] = expf(rsc[h*Dd+e0+1] * k4.y * rk);
    k_lds[t*192 + is*24 + c4*4+2] = expf(rsc[h*Dd+e0+2] * k4.z * rk);
    k_lds[t*192 + is*24 + c4*4+3] = expf(rsc[h*Dd+e0+3] * k4.w * rk);
  }
  #pragma unroll
  for (int c4 = 0; c4 < 4; ++c4) {
    float4 v4 = *(const float4*)(v + rowbase + c4*4);
    int j0 = is*16 + c4*4;
    vfrag[(t>>3)*1152 + (j0+0)*8 + (t&7)] = f2bf(v4.x);
    vfrag[(t>>3)*1152 + (j0+1)*8 + (t&7)] = f2bf(v4.y);
    vfrag[(t>>3)*1152 + (j0+2)*8 + (t&7)] = f2bf(v4.z);
    vfrag[(t>>3)*1152 + (j0+3)*8 + (t&7)] = f2bf(v4.w);
  }
  if (tid < 32) vfrag[(tid>>3)*1152 + 128*8 + (tid&7)] = 0x3F80;
  if (tid < 240) {
    #pragma unroll
    for (int u = 0; u < 2; ++u) {
      int e = tid*2 + u;
      int ig = e / 120, rem = e % 120;
      vfrag[ig*1152 + (129 + rem/8)*8 + (rem&7)] = 0;
    }
  }
  __syncthreads();

  {
    float lamr[16], wrun[16];
    #pragma unroll
    for (int e4 = 0; e4 < 4; ++e4) {
      float4 l4 = *(const float4*)&lam_lds[is*16 + e4*4];
      lamr[e4*4+0]=l4.x; lamr[e4*4+1]=l4.y; lamr[e4*4+2]=l4.z; lamr[e4*4+3]=l4.w;
    }
    #pragma unroll
    for (int e = 0; e < 16; ++e) wrun[e] = 1.f;
    const int smax = (w << 3) + 7;
    for (int s = smax; s >= 0; --s) {
      float dot = 0.f;
      #pragma unroll
      for (int c4 = 0; c4 < 4; ++c4) {
        float4 k4 = *(const float4*)&k_lds[s*192 + is*24 + c4*4];
        dot = fmaf(qv[c4*4+0], k4.x*wrun[c4*4+0], dot);
        dot = fmaf(qv[c4*4+1], k4.y*wrun[c4*4+1], dot);
        dot = fmaf(qv[c4*4+2], k4.z*wrun[c4*4+2], dot);
        dot = fmaf(qv[c4*4+3], k4.w*wrun[c4*4+3], dot);
      }
      dot += __shfl_xor(dot, 1);
      dot += __shfl_xor(dot, 2);
      dot += __shfl_xor(dot, 4);
      bool act = (s <= t);
      if (act && is == 0) P32[t*33 + s] = dot;
      if (act) {
        #pragma unroll
        for (int e = 0; e < 16; ++e) wrun[e] *= lamr[e];
      }
    }
  }
  __syncthreads();
  {
    int tt = tid >> 3, s0 = (tid & 7) * 4;
    #pragma unroll
    for (int ss = 0; ss < 4; ++ss) {
      int s = s0 + ss;
      float val = (s <= tt) ? P32[tt*33 + s] : 0.f;
      pfrag[tt*32 + (((s>>3) ^ (tt&3))<<3) + (s&7)] = f2bf(val);
    }
  }
  __syncthreads();

  const int tau = w >> 1;
  const int jt0 = (w & 1) ? 5 : 0;
  const int njt = (w & 1) ? 4 : 5;
  const int rl = l & 15, kg = l >> 4;
  const int trow = tau*16 + rl;
  const u16* augb_base = Augb + ((size_t)c*16 + bh)*AUGB_CB;

  bf16x8 aq[4];
  #pragma unroll
  for (int kk = 0; kk < 4; ++kk)
    aq[kk] = *(const bf16x8*)&qfrag[trow*128 + ((((kk<<2)+kg) ^ (trow&7))<<3)];
  bf16x8 ap = *(const bf16x8*)&pfrag[trow*32 + ((kg ^ (trow&3))<<3)];

  f32x4 acc[5];
  #pragma unroll
  for (int u = 0; u < 5; ++u) acc[u] = (f32x4){0.f,0.f,0.f,0.f};

  #pragma unroll
  for (int u = 0; u < 5; ++u) {
    if (u < njt) {
      int jt = jt0 + u;
      #pragma unroll
      for (int kk = 0; kk < 4; ++kk) {
        bf16x8 bfr = *(const bf16x8*)&augb_base[(size_t)(((kk<<2)+kg)*1152 + (jt*16 + rl)*8)];
        acc[u] = __builtin_amdgcn_mfma_f32_16x16x32_bf16(aq[kk], bfr, acc[u], 0, 0, 0);
      }
      bf16x8 bv = *(const bf16x8*)&vfrag[kg*1152 + (jt*16 + rl)*8];
      acc[u] = __builtin_amdgcn_mfma_f32_16x16x32_bf16(ap, bv, acc[u], 0, 0, 0);
    }
  }
  if ((w & 1) && rl == 0) {
    #pragma unroll
    for (int r = 0; r < 4; ++r) zbuf[tau*16 + kg*4 + r] = acc[3][r];
  }
  __syncthreads();

  const int nout = (w & 1) ? 3 : 5;
  #pragma unroll
  for (int u = 0; u < 5; ++u) {
    if (u < nout) {
      int jt = jt0 + u;
      int cc = h*Dd + jt*16 + rl;
      #pragma unroll
      for (int r = 0; r < 4; ++r) {
        int tr = tau*16 + kg*4 + r;
        int m = b*Tt + c*CL + tr;
        float zv = zbuf[tr];
        float gv = gmat[(size_t)m*Cc + cc];
        out[((size_t)(cc >> 3) * Mrows + m) * 8 + (cc & 7)] = f2bf(gv * acc[u][r] / zv);
      }
    }
  }
}

extern "C" void kernel_launch(void* const* d_in, const int* in_sizes, int n_in,
                              void* d_out, int out_size, void* d_ws, size_t ws_size,
                              hipStream_t stream) {
  const float* x    = (const float*)d_in[0];
  const float* ln1g = (const float*)d_in[1];
  const float* ln1b = (const float*)d_in[2];
  const float* ln2g = (const float*)d_in[3];
  const float* ln2b = (const float*)d_in[4];
  const float* td   = (const float*)d_in[5];
  const float* tmq  = (const float*)d_in[6];
  const float* tmk  = (const float*)d_in[7];
  const float* tmv  = (const float*)d_in[8];
  const float* tmg  = (const float*)d_in[9];
  const float* Wq   = (const float*)d_in[10];
  const float* Wk   = (const float*)d_in[11];
  const float* Wv   = (const float*)d_in[12];
  const float* Wg   = (const float*)d_in[13];
  const float* Wo   = (const float*)d_in[14];
  const float* rsc  = (const float*)d_in[15];
  const float* W1   = (const float*)d_in[16];
  const float* W2   = (const float*)d_in[17];
  float* ws = (float*)d_ws;
  const size_t E = (size_t)Mrows*Cc;           // 2,097,152
  float* s0 = ws;          // q raw -> W2 partial0
  float* s1 = ws + E;      // k raw -> W2 p1
  float* s2 = ws + 2*E;    // v -> Wo p0 -> W2 p2
  float* s3 = ws + 3*E;    // g -> Wo p1 -> W2 p3
  float* x1 = ws + 4*E;
  u16* xqb = (u16*)(ws + 5*E);
  u16* xkb = xqb + E;
  u16* xvb = xkb + E;
  u16* xgb = xvb + E;
  u16* wreg = (u16*)(ws + 7*E);
  u16* Wqb = wreg;                          // 5 x 262144
  u16* Wob = wreg + 4*262144;
  u16* W1b = wreg + 5*262144;               // 1,048,576
  u16* W2b = W1b + 1048576;                 // 1,048,576
  u16* Augl = W2b + 1048576;                // NC*16*AUGB_CB = 9,437,184 u16
  u16* Augb = Augl + (size_t)NC*16*AUGB_CB; // 9,437,184 u16
  float* ssqp = (float*)(Augb + (size_t)NC*16*AUGB_CB);  // [2][4][4096]
  u16* midb  = Augl;                        // reuse after combine (W1 out, 16.8MB)
  u16* gattb = xqb;
  u16* h2b   = xkb;

  wconv_all_kernel<<<1664,256,0,stream>>>(Wq, Wk, Wv, Wg, Wo, W1, W2, Wqb);
  ln1mix_kernel<<<Mrows,256,0,stream>>>(x, ln1g, ln1b, tmq,tmk,tmv,tmg,
                                        xqb,xkb,xvb,xgb);
  gemm_qkvg<<<dim3(4,32,4),256,0,stream>>>(xqb, Wqb, s0, ssqp);            // q,k,v,g + ssq
  chunk_state_kernel<<<16*NC,256,0,stream>>>(s1, s2, td, rsc, ssqp, Augl);
  combine_kernel<<<dim3(65,16),256,0,stream>>>(Augl, td, Augb);
  scan_mfma_kernel<<<16*NC,256,0,stream>>>(s0, s1, s2, td, rsc, ssqp, Augb, s3, gattb);
  gemm_wo<<<dim3(4,32,2),256,0,stream>>>(gattb, Wob, s2);                  // p0,p1 -> s2,s3
  ln2b_kernel<<<Mrows,256,0,stream>>>(x, s2, s3, ln2g, ln2b, x1, h2b);
  gemm_w1<<<dim3(16,32),256,0,stream>>>(h2b, W1b, midb);
  gemm_w2<<<dim3(4,32,4),256,0,stream>>>(midb, W2b, s0);                   // partials s0..s3
  reduce4_kernel<<<2048,256,0,stream>>>(x1, s0, (float*)d_out);
}